// Round 1
// baseline (566.839 us; speedup 1.0000x reference)
//
#include <hip/hip_runtime.h>

#define NQ 1764
#define DIM 256

#define KT 32
#define NTILES 56            // ceil(1764/32)
#define RM_STRIDE 260        // halfwords; row-major m tile, padded vs 256
#define TR_STRIDE 36         // halfwords; transposed m tile, padded vs 32
#define P_STRIDE 40          // halfwords; per-wave P scratch, 16B-aligned rows
#define RM_OFF 0
#define TR_OFF (32 * RM_STRIDE)
#define P_OFF (TR_OFF + DIM * TR_STRIDE)
#define SM_TOTAL (P_OFF + 4 * 32 * P_STRIDE)   // 22656 hw = 45312 B

typedef __attribute__((ext_vector_type(4))) short short4v;
typedef __attribute__((ext_vector_type(8))) short short8v;
typedef __attribute__((ext_vector_type(4))) float float4v;

static __device__ __forceinline__ ushort f2bf(float f) {
  union { float f; unsigned u; } v; v.f = f;
  return (ushort)((v.u + 0x7FFFu + ((v.u >> 16) & 1u)) >> 16);  // RNE
}

// One block = 4 waves = 128 queries of one batch. Each wave owns 32 queries
// (two 16-row MFMA sub-tiles) and streams all 1764 keys in 32-wide tiles.
// Softmax without max-subtraction (scores are small); w_lin term cancels.
__global__ __launch_bounds__(256, 2)
void attn_fused(const float* __restrict__ x, const float* __restrict__ mg,
                const int* __restrict__ maskg, const float* __restrict__ scale,
                float* __restrict__ out)
{
  __shared__ ushort sm[SM_TOTAL];
  const int tid  = threadIdx.x;
  const int w    = tid >> 6;
  const int lane = tid & 63;
  const int l15  = lane & 15;
  const int quad = lane >> 4;

  const int b     = blockIdx.x & 15;   // batch in low bits -> same batch maps to same XCD mod 8
  const int qblk  = blockIdx.x >> 4;   // 0..13
  const int qbase = qblk * 128 + w * 32;

  const float* xb  = x  + (size_t)b * NQ * DIM;
  const float* mb  = mg + (size_t)b * NQ * DIM;
  const int*   mkb = maskg + (size_t)b * NQ;
  float*       ob  = out + (size_t)b * NQ * (2 * DIM);

  // ---- resident Q fragments: Q = x * dot_scale, bf16, MFMA A-layout ----
  // A[m=lane&15][k=quad*8+j] per 32-wide d-chunk kk
  short8v qa[2][8];
  #pragma unroll
  for (int kk = 0; kk < 8; ++kk) {
    const int dof = kk * 32 + quad * 8;
    const float4v s0 = *(const float4v*)(scale + dof);
    const float4v s1 = *(const float4v*)(scale + dof + 4);
    #pragma unroll
    for (int qs = 0; qs < 2; ++qs) {
      int q = qbase + qs * 16 + l15;
      q = q < NQ ? q : NQ - 1;                 // clamp; stores are guarded
      const float* xr = xb + (size_t)q * DIM + dof;
      const float4v x0 = *(const float4v*)(xr);
      const float4v x1 = *(const float4v*)(xr + 4);
      union { short8v v; short e[8]; } u;
      #pragma unroll
      for (int j = 0; j < 4; ++j) {
        u.e[j]     = (short)f2bf(x0[j] * s0[j]);
        u.e[j + 4] = (short)f2bf(x1[j] * s1[j]);
      }
      qa[qs][kk] = u.v;
    }
  }

  float4v o[2][16];
  #pragma unroll
  for (int qs = 0; qs < 2; ++qs)
    #pragma unroll
    for (int dt = 0; dt < 16; ++dt)
      o[qs][dt] = (float4v){0.f, 0.f, 0.f, 0.f};
  float l_part[2][4] = {{0.f,0.f,0.f,0.f},{0.f,0.f,0.f,0.f}};

  #pragma unroll 1
  for (int kt = 0; kt < NTILES; ++kt) {
    const int k0 = kt * KT;
    __syncthreads();   // protect previous tile's readers

    // ---- stage m tile row-major [key][d], bf16 (for QK^T B-frags) ----
    #pragma unroll
    for (int i = 0; i < 8; ++i) {
      const int row = i * 4 + w;
      int gr = k0 + row; gr = gr < NQ ? gr : NQ - 1;
      const float4v v = *(const float4v*)(mb + (size_t)gr * DIM + lane * 4);
      union { short4v v4; short e[4]; } h;
      #pragma unroll
      for (int j = 0; j < 4; ++j) h.e[j] = (short)f2bf(v[j]);
      *(short4v*)&sm[RM_OFF + row * RM_STRIDE + lane * 4] = h.v4;
    }
    // ---- stage m tile transposed [d][key], bf16 (for PV B-frags) ----
    #pragma unroll
    for (int i = 0; i < 4; ++i) {
      const int r0 = w * 8 + i * 2;
      int g0 = k0 + r0;     g0 = g0 < NQ ? g0 : NQ - 1;
      int g1 = k0 + r0 + 1; g1 = g1 < NQ ? g1 : NQ - 1;
      #pragma unroll
      for (int dd = 0; dd < 4; ++dd) {
        const int d = dd * 64 + lane;
        const float a0 = mb[(size_t)g0 * DIM + d];
        const float a1 = mb[(size_t)g1 * DIM + d];
        const unsigned pk = (unsigned)f2bf(a0) | ((unsigned)f2bf(a1) << 16);
        *(unsigned*)&sm[TR_OFF + d * TR_STRIDE + r0] = pk;
      }
    }
    __syncthreads();

    // mask for this tile's 32 keys (col l15 of each 16-wide subtile)
    bool mv[2];
    #pragma unroll
    for (int ks = 0; ks < 2; ++ks) {
      const int kk2 = k0 + ks * 16 + l15;
      mv[ks] = (kk2 < NQ) && (mkb[kk2] != 0);
    }

    // ---- S = Q·m^T (bf16 MFMA), p = mask ? exp(s) : 0, write P to LDS ----
    #pragma unroll
    for (int qs = 0; qs < 2; ++qs) {
      #pragma unroll
      for (int ks = 0; ks < 2; ++ks) {
        float4v s = (float4v){0.f, 0.f, 0.f, 0.f};
        #pragma unroll
        for (int kk = 0; kk < 8; ++kk) {
          // B[k=d][n=key]: row (ks*16+l15) of row-major tile, 8 contiguous d
          const ushort* bp = &sm[RM_OFF + (ks * 16 + l15) * RM_STRIDE + kk * 32 + quad * 8];
          union { short8v v8; short4v v4[2]; } ub;
          ub.v4[0] = *(const short4v*)bp;
          ub.v4[1] = *(const short4v*)(bp + 4);
          s = __builtin_amdgcn_mfma_f32_16x16x32_bf16(qa[qs][kk], ub.v8, s, 0, 0, 0);
        }
        // C layout: row = quad*4+r, col = l15
        #pragma unroll
        for (int r = 0; r < 4; ++r) {
          const float p = mv[ks] ? exp2f(s[r] * 1.44269504089f) : 0.0f;
          l_part[qs][r] += p;
          sm[P_OFF + (w * 32 + qs * 16 + quad * 4 + r) * P_STRIDE + ks * 16 + l15] = f2bf(p);
        }
      }
    }

    // ---- O += P·m (P re-read in A-layout; same wave, no barrier needed) ----
    #pragma unroll
    for (int qs = 0; qs < 2; ++qs) {
      const short8v pa = *(const short8v*)&sm[P_OFF + (w * 32 + qs * 16 + l15) * P_STRIDE + quad * 8];
      #pragma unroll
      for (int dt = 0; dt < 16; ++dt) {
        // B[k=key][n=d]: row (dt*16+l15) of transposed tile, 8 contiguous keys
        const ushort* bp = &sm[TR_OFF + (dt * 16 + l15) * TR_STRIDE + quad * 8];
        union { short8v v8; short4v v4[2]; } ub;
        ub.v4[0] = *(const short4v*)bp;
        ub.v4[1] = *(const short4v*)(bp + 4);
        o[qs][dt] = __builtin_amdgcn_mfma_f32_16x16x32_bf16(pa, ub.v8, o[qs][dt], 0, 0, 0);
      }
    }
  }

  // ---- row sums: reduce partial l across the 16 lanes of each quad ----
  float inv_l[2][4];
  #pragma unroll
  for (int qs = 0; qs < 2; ++qs)
    #pragma unroll
    for (int r = 0; r < 4; ++r) {
      float l = l_part[qs][r];
      l += __shfl_xor(l, 1);
      l += __shfl_xor(l, 2);
      l += __shfl_xor(l, 4);
      l += __shfl_xor(l, 8);
      inv_l[qs][r] = 1.0f / l;
    }

  // ---- store attention half: out[b][q][256 + d] ----
  #pragma unroll
  for (int qs = 0; qs < 2; ++qs)
    #pragma unroll
    for (int r = 0; r < 4; ++r) {
      const int q = qbase + qs * 16 + quad * 4 + r;
      if (q < NQ) {
        float* orow = ob + (size_t)q * (2 * DIM) + DIM + l15;
        #pragma unroll
        for (int dt = 0; dt < 16; ++dt)
          orow[dt * 16] = o[qs][dt][r] * inv_l[qs][r];
      }
    }

  // ---- copy x into first half of concat: out[b][q][0..255] ----
  for (int i = 0; i < 32; ++i) {
    const int q = qbase + i;
    if (q < NQ) {
      const float4v v = *(const float4v*)(xb + (size_t)q * DIM + lane * 4);
      *(float4v*)(ob + (size_t)q * (2 * DIM) + lane * 4) = v;
    }
  }
}

extern "C" void kernel_launch(void* const* d_in, const int* in_sizes, int n_in,
                              void* d_out, int out_size, void* d_ws, size_t ws_size,
                              hipStream_t stream) {
  const float* x     = (const float*)d_in[0];
  const float* mem   = (const float*)d_in[1];
  const int*   mask  = (const int*)d_in[2];
  // d_in[3] = w_lin: mathematically cancels in softmax (per-row constant) — unused
  const float* scale = (const float*)d_in[4];
  float* out = (float*)d_out;

  // 16 batches x 14 query-blocks; batch in low bits for XCD L2 affinity
  attn_fused<<<dim3(16 * 14), dim3(256), 0, stream>>>(x, mem, mask, scale, out);
}

// Round 2
// 463.628 us; speedup vs baseline: 1.2226x; 1.2226x over previous
//
#include <hip/hip_runtime.h>

#define NQ 1764
#define DIM 256

#define KT 64
#define NTILES 28            // ceil(1764/64)
#define RM_STRIDE 264        // hw; 64-key row-major tile rows, 16B-aligned (528 B)
#define TR_STRIDE 72         // hw; transposed tile rows (144 B, 16B-aligned)
#define P_STRIDE 32          // hw; per-wave P scratch (64 B rows, 16B-aligned)
#define RM_OFF 0
#define TR_OFF (64 * RM_STRIDE)                 // 16896
#define P_OFF (TR_OFF + DIM * TR_STRIDE)        // 35328
#define SM_TOTAL (P_OFF + 8 * 16 * P_STRIDE)    // 39424 hw = 78848 B -> 2 blocks/CU

typedef __attribute__((ext_vector_type(4))) short short4v;
typedef __attribute__((ext_vector_type(8))) short short8v;
typedef __attribute__((ext_vector_type(4))) float float4v;

static __device__ __forceinline__ ushort f2bf(float f) {
  union { float f; unsigned u; } v; v.f = f;
  return (ushort)((v.u + 0x7FFFu + ((v.u >> 16) & 1u)) >> 16);  // RNE
}

// Block = 8 waves = 512 threads. Wave w owns queries qblk*64 + (w&3)*16 and
// key-half (w>>2) of each shared 64-key LDS tile. Waves w and w+4 combine
// their partial (O, l) through LDS at the end. Softmax needs no max-subtract
// (|s| small); w_lin additive term cancels in softmax.
__global__ __launch_bounds__(512, 4)
void attn_fused(const float* __restrict__ x, const float* __restrict__ mg,
                const int* __restrict__ maskg, const float* __restrict__ scale,
                float* __restrict__ out)
{
  __shared__ ushort sm[SM_TOTAL];
  const int tid  = threadIdx.x;
  const int w    = tid >> 6;     // 0..7
  const int lane = tid & 63;
  const int l15  = lane & 15;
  const int quad = lane >> 4;
  const int kh   = w >> 2;       // key half 0/1
  const int wq   = w & 3;        // query sub-block 0..3

  const int b     = blockIdx.x & 15;   // batch in low bits -> XCD L2 affinity
  const int qblk  = blockIdx.x >> 4;   // 0..27
  const int qbase = qblk * 64 + wq * 16;

  const float* xb  = x  + (size_t)b * NQ * DIM;
  const float* mb  = mg + (size_t)b * NQ * DIM;
  const int*   mkb = maskg + (size_t)b * NQ;
  float*       ob  = out + (size_t)b * NQ * (2 * DIM);

  // ---- resident Q fragments: Q = x * dot_scale, bf16, MFMA A-layout ----
  short8v qa[8];
  {
    int q = qbase + l15;
    q = q < NQ ? q : NQ - 1;                   // clamp; stores are guarded
    const float* xr = xb + (size_t)q * DIM;
    #pragma unroll
    for (int kk = 0; kk < 8; ++kk) {
      const int dof = kk * 32 + quad * 8;
      const float4v s0 = *(const float4v*)(scale + dof);
      const float4v s1 = *(const float4v*)(scale + dof + 4);
      const float4v x0 = *(const float4v*)(xr + dof);
      const float4v x1 = *(const float4v*)(xr + dof + 4);
      union { short8v v; short e[8]; } u;
      #pragma unroll
      for (int j = 0; j < 4; ++j) {
        u.e[j]     = (short)f2bf(x0[j] * s0[j]);
        u.e[j + 4] = (short)f2bf(x1[j] * s1[j]);
      }
      qa[kk] = u.v;
    }
  }

  float4v o[16];
  #pragma unroll
  for (int dt = 0; dt < 16; ++dt) o[dt] = (float4v){0.f, 0.f, 0.f, 0.f};
  float l_part[4] = {0.f, 0.f, 0.f, 0.f};

  #pragma unroll 1
  for (int kt = 0; kt < NTILES; ++kt) {
    const int k0 = kt * KT;
    __syncthreads();   // protect previous tile's readers

    // ---- stage 64-key m tile row-major [key][d], bf16 ----
    #pragma unroll
    for (int i = 0; i < 8; ++i) {
      const int row = i * 8 + w;
      int gr = k0 + row; gr = gr < NQ ? gr : NQ - 1;
      const float4v v = *(const float4v*)(mb + (size_t)gr * DIM + lane * 4);
      union { short4v v4; short e[4]; } h;
      #pragma unroll
      for (int j = 0; j < 4; ++j) h.e[j] = (short)f2bf(v[j]);
      *(short4v*)&sm[RM_OFF + row * RM_STRIDE + lane * 4] = h.v4;
    }
    // ---- stage transposed [d][key], bf16, keys packed in dword pairs ----
    #pragma unroll
    for (int i = 0; i < 4; ++i) {
      const int r0 = w * 8 + i * 2;
      int g0 = k0 + r0;     g0 = g0 < NQ ? g0 : NQ - 1;
      int g1 = k0 + r0 + 1; g1 = g1 < NQ ? g1 : NQ - 1;
      #pragma unroll
      for (int dd = 0; dd < 4; ++dd) {
        const int d = dd * 64 + lane;
        const float a0 = mb[(size_t)g0 * DIM + d];
        const float a1 = mb[(size_t)g1 * DIM + d];
        const unsigned pk = (unsigned)f2bf(a0) | ((unsigned)f2bf(a1) << 16);
        *(unsigned*)&sm[TR_OFF + d * TR_STRIDE + r0] = pk;
      }
    }
    __syncthreads();

    // mask for this wave's 32 keys
    bool mv[2];
    #pragma unroll
    for (int ks = 0; ks < 2; ++ks) {
      const int kk2 = k0 + kh * 32 + ks * 16 + l15;
      mv[ks] = (kk2 < NQ) && (mkb[kk2] != 0);
    }

    // ---- S = Q·m^T, p = mask ? exp(s) : 0, write P to wave-private LDS ----
    #pragma unroll
    for (int ks = 0; ks < 2; ++ks) {
      float4v s = (float4v){0.f, 0.f, 0.f, 0.f};
      #pragma unroll
      for (int kk = 0; kk < 8; ++kk) {
        const ushort* bp = &sm[RM_OFF + (kh * 32 + ks * 16 + l15) * RM_STRIDE + kk * 32 + quad * 8];
        union { short8v v8; short4v v4[2]; } ub;
        ub.v4[0] = *(const short4v*)bp;
        ub.v4[1] = *(const short4v*)(bp + 4);
        s = __builtin_amdgcn_mfma_f32_16x16x32_bf16(qa[kk], ub.v8, s, 0, 0, 0);
      }
      #pragma unroll
      for (int r = 0; r < 4; ++r) {
        const float p = mv[ks] ? exp2f(s[r] * 1.44269504089f) : 0.0f;
        l_part[r] += p;
        sm[P_OFF + (w * 16 + quad * 4 + r) * P_STRIDE + ks * 16 + l15] = f2bf(p);
      }
    }

    // ---- O += P·m (same wave wrote P; in-wave LDS ordering suffices) ----
    {
      const short8v pa = *(const short8v*)&sm[P_OFF + (w * 16 + l15) * P_STRIDE + quad * 8];
      #pragma unroll
      for (int dt = 0; dt < 16; ++dt) {
        const ushort* bp = &sm[TR_OFF + (dt * 16 + l15) * TR_STRIDE + kh * 32 + quad * 8];
        union { short8v v8; short4v v4[2]; } ub;
        ub.v4[0] = *(const short4v*)bp;
        ub.v4[1] = *(const short4v*)(bp + 4);
        o[dt] = __builtin_amdgcn_mfma_f32_16x16x32_bf16(pa, ub.v8, o[dt], 0, 0, 0);
      }
    }
  }

  // ---- reduce l across the 16 lanes of each quad ----
  float lsum[4];
  #pragma unroll
  for (int r = 0; r < 4; ++r) {
    float l = l_part[r];
    l += __shfl_xor(l, 1);
    l += __shfl_xor(l, 2);
    l += __shfl_xor(l, 4);
    l += __shfl_xor(l, 8);
    lsum[r] = l;
  }

  // ---- combine key-half partials: waves 4..7 publish, waves 0..3 merge ----
  __syncthreads();                       // staging readers done
  float* fo = (float*)sm;                // [4 waves][16 q][260] padded rows
  float* fl = fo + 4 * 16 * 260;         // [4][16] l partials
  if (w >= 4) {
    const int wi = w - 4;
    #pragma unroll
    for (int dt = 0; dt < 16; ++dt)
      #pragma unroll
      for (int r = 0; r < 4; ++r)
        fo[(wi * 16 + quad * 4 + r) * 260 + dt * 16 + l15] = o[dt][r];
    if (l15 == 0)
      #pragma unroll
      for (int r = 0; r < 4; ++r)
        fl[wi * 16 + quad * 4 + r] = lsum[r];
  }
  __syncthreads();
  if (w < 4) {
    #pragma unroll
    for (int r = 0; r < 4; ++r) {
      const int q = qbase + quad * 4 + r;
      const float inv = 1.0f / (lsum[r] + fl[w * 16 + quad * 4 + r]);
      if (q < NQ) {
        float* orow = ob + (size_t)q * (2 * DIM) + DIM + l15;
        #pragma unroll
        for (int dt = 0; dt < 16; ++dt)
          orow[dt * 16] = (o[dt][r] + fo[(w * 16 + quad * 4 + r) * 260 + dt * 16 + l15]) * inv;
      }
    }
  }

  // ---- copy x into first half of concat (all 8 waves) ----
  #pragma unroll
  for (int i = 0; i < 8; ++i) {
    const int q = qblk * 64 + i * 8 + w;
    if (q < NQ) {
      const float4v v = *(const float4v*)(xb + (size_t)q * DIM + lane * 4);
      *(float4v*)(ob + (size_t)q * (2 * DIM) + lane * 4) = v;
    }
  }
}

extern "C" void kernel_launch(void* const* d_in, const int* in_sizes, int n_in,
                              void* d_out, int out_size, void* d_ws, size_t ws_size,
                              hipStream_t stream) {
  const float* x     = (const float*)d_in[0];
  const float* mem   = (const float*)d_in[1];
  const int*   mask  = (const int*)d_in[2];
  // d_in[3] = w_lin: cancels in softmax (per-row constant) — unused
  const float* scale = (const float*)d_in[4];
  float* out = (float*)d_out;

  // 16 batches x 28 query-blocks of 64 queries; batch in low bits (XCD affinity)
  attn_fused<<<dim3(16 * 28), dim3(512), 0, stream>>>(x, mem, mask, scale, out);
}